// Round 11
// baseline (367.204 us; speedup 1.0000x reference)
//
#include <hip/hip_runtime.h>
#include <hip/hip_bf16.h>
#include <stdint.h>

typedef unsigned short bf16_t;
typedef __attribute__((ext_vector_type(4))) short s4v;
typedef __attribute__((ext_vector_type(8))) short short8;
typedef __attribute__((ext_vector_type(4))) float f32x4;

__device__ __forceinline__ bf16_t f2b(float f) {
    union { float f; uint32_t u; } v; v.f = f;
    uint32_t u = v.u;
    return (bf16_t)((u + 0x7FFFu + ((u >> 16) & 1u)) >> 16);
}

__device__ __forceinline__ float b2f(bf16_t b) {
    union { uint32_t u; float f; } v;
    v.u = ((uint32_t)b) << 16;
    return v.f;
}

// ---------- all input conversions in ONE launch ----------
// blocks 0..8191: x (2097152 float4s) ; blocks 8192..8959: 3 weight mats
__global__ __launch_bounds__(256) void cvt_all(const float* __restrict__ x,
                                               bf16_t* __restrict__ Xb,
                                               const float* __restrict__ a,
                                               const float* __restrict__ b,
                                               const float* __restrict__ c,
                                               bf16_t* __restrict__ Wb) {
    int i = blockIdx.x * 256 + threadIdx.x;
    if (i < 2097152) {
        float4 f = ((const float4*)x)[i];
        ushort4 o;
        o.x = f2b(f.x); o.y = f2b(f.y); o.z = f2b(f.z); o.w = f2b(f.w);
        ((ushort4*)Xb)[i] = o;
    } else {
        int j = i - 2097152;              // 0..196607
        const int which = j >> 16;
        const int idx   = j & 65535;
        const float* src = (which == 0) ? a : (which == 1) ? b : c;
        float4 f = ((const float4*)src)[idx];
        ushort4 o;
        o.x = f2b(f.x); o.y = f2b(f.y); o.z = f2b(f.z); o.w = f2b(f.w);
        ((ushort4*)Wb)[j] = o;
    }
}

__device__ __forceinline__ void lds_dma16(const void* g, void* l) {
    __builtin_amdgcn_global_load_lds(
        (const __attribute__((address_space(1))) void*)g,
        (__attribute__((address_space(3))) void*)l, 16, 0, 0);
}

// BK=64 swizzle contract: LDS[row][ch] holds global chunk (ch ^ (row&7));
// reader wanting global chunk g of row r reads LDS[r][g ^ (r&7)].
// 2-phase loop contract (T3 minimum recipe):
//   prologue: STAGE(buf0, kt=0); barrier.
//   iter kt:  STAGE(buf[cur^1], kt+1); ds_read+MFMA from buf[cur];
//             __syncthreads(); cur ^= 1.   One barrier per K-step.

// ---------- projections: Q/K/V fused (1536 blocks) + bias f32->bf16 streamed
// into the k-loop's idle memory slots (r10-verified net win) ----------
__global__ __launch_bounds__(256)
void proj_all(const bf16_t* __restrict__ Xb, const bf16_t* __restrict__ Wb,
              const float* __restrict__ qb, const float* __restrict__ kb,
              const float* __restrict__ vb,
              bf16_t* __restrict__ Qb, bf16_t* __restrict__ Kb,
              bf16_t* __restrict__ Vt,
              const float* __restrict__ biasf, bf16_t* __restrict__ biasb)
{
    __shared__ __align__(16) bf16_t lds[2][16384];   // 64 KB: 2 x (A 16KB | B 16KB)

    const int tid  = threadIdx.x;
    const int bid  = blockIdx.x;
    const int lane = tid & 63;
    const int w    = tid >> 6;
    const int wm   = w & 1, wn = w >> 1;
    const int ll   = lane & 15;
    const int quad = lane >> 4;

    // xcd x owns m-panels [16x..16x+15]; inner = 4n x 3z per panel.
    const int x     = bid & 7;
    const int g     = bid >> 3;        // 0..191
    const int mi    = x * 16 + g / 12; // 0..127
    const int inner = g % 12;
    const int m0 = mi * 128;
    const int n0 = (inner & 3) * 128;
    const int z  = inner >> 2;         // 0..2

    const bf16_t* A = Xb;
    const bf16_t* B = Wb + z * 262144;

    auto stage = [&](int kt, int b) {
#pragma unroll
        for (int c = 0; c < 4; ++c) {
            const int base = (c * 4 + w) * 64;
            const int slot = base + lane;
            const int row  = slot >> 3;
            const int kc   = ((slot & 7) ^ (row & 7)) << 3;
            lds_dma16(A + (size_t)(m0 + row) * 512 + kt * 64 + kc, (char*)&lds[b][0]    + base * 16);
            lds_dma16(B + (size_t)(n0 + row) * 512 + kt * 64 + kc, (char*)&lds[b][8192] + base * 16);
        }
    };

    f32x4 acc[4][4];
#pragma unroll
    for (int i = 0; i < 4; i++)
#pragma unroll
        for (int j = 0; j < 4; j++) acc[i][j] = (f32x4){0.f, 0.f, 0.f, 0.f};

    stage(0, 0);
    __syncthreads();
    int cur = 0;
    for (int kt = 0; kt < 8; ++kt) {
        if (kt < 7) stage(kt + 1, cur ^ 1);

        // ---- bias f32->bf16 chunk: independent mem ops, hidden under MFMA.
        {
            const int idx = (bid * 8 + kt) * 256 + tid;     // < 3145728
            float4 f = ((const float4*)biasf)[idx];
            ushort4 o;
            o.x = f2b(f.x); o.y = f2b(f.y); o.z = f2b(f.z); o.w = f2b(f.w);
            ((ushort4*)biasb)[idx] = o;
            const int idx2 = idx + 3145728;
            if (idx2 < 4194304) {
                float4 f2 = ((const float4*)biasf)[idx2];
                ushort4 o2;
                o2.x = f2b(f2.x); o2.y = f2b(f2.y); o2.z = f2b(f2.z); o2.w = f2b(f2.w);
                ((ushort4*)biasb)[idx2] = o2;
            }
        }

        const bf16_t* lsA = &lds[cur][0];
        const bf16_t* lsB = &lds[cur][8192];
#pragma unroll
        for (int t = 0; t < 2; t++) {
            short8 af[4], bf[4];
#pragma unroll
            for (int i = 0; i < 4; i++) {
                const int ri = wm * 64 + i * 16 + ll;
                const int rj = wn * 64 + i * 16 + ll;
                af[i] = *(const short8*)(lsA + ri * 64 + (((t * 4 + quad) ^ (ll & 7)) << 3));
                bf[i] = *(const short8*)(lsB + rj * 64 + (((t * 4 + quad) ^ (ll & 7)) << 3));
            }
#pragma unroll
            for (int i = 0; i < 4; i++)
#pragma unroll
                for (int j = 0; j < 4; j++)
                    acc[i][j] = __builtin_amdgcn_mfma_f32_16x16x32_bf16(af[i], bf[j], acc[i][j], 0, 0, 0);
        }
        __syncthreads();
        cur ^= 1;
    }

    // ---- epilogue: bounce through LDS for coalesced 16B stores ----
    bf16_t* wbuf = &lds[0][0] + w * 4096;     // 64x64 bf16 per wave (32 KB in buf0)
    const float inv = 0.044194173824159216f;  // 1/sqrt(512)

    if (z != 2) {
        const float* bptr = (z == 0) ? qb : kb;
        const float scl   = (z == 0) ? inv : 1.0f;
#pragma unroll
        for (int j = 0; j < 4; j++) {
            const int colL = j * 16 + ll;
            const float bv = bptr[n0 + wn * 64 + colL];
#pragma unroll
            for (int i = 0; i < 4; i++) {
                f32x4 a = acc[i][j];
#pragma unroll
                for (int r = 0; r < 4; r++) {
                    const int rowL = i * 16 + quad * 4 + r;
                    wbuf[rowL * 64 + (colL ^ ((rowL & 7) << 3))] = f2b((a[r] + bv) * scl);
                }
            }
        }
        __syncthreads();
        bf16_t* dst = (z == 0) ? Qb : Kb;
        const int rowg0 = m0 + wm * 64;
        const int colg0 = n0 + wn * 64;
#pragma unroll
        for (int k = 0; k < 8; k++) {
            const int rowL = (lane >> 3) + k * 8;
            const int c0   = (lane & 7) * 8;
            short8 vv = *(const short8*)(wbuf + rowL * 64 + (c0 ^ ((rowL & 7) << 3)));
            *(short8*)(dst + (size_t)(rowg0 + rowL) * 512 + colg0 + c0) = vv;
        }
    } else {
        // V: store transposed Vt[b][d][s]; bounce col-major (d-major)
#pragma unroll
        for (int j = 0; j < 4; j++) {
            const int d = j * 16 + ll;
            const float bv = vb[n0 + wn * 64 + d];
#pragma unroll
            for (int i = 0; i < 4; i++) {
                f32x4 a = acc[i][j];
                s4v pk;
                pk[0] = (short)f2b(a[0] + bv);
                pk[1] = (short)f2b(a[1] + bv);
                pk[2] = (short)f2b(a[2] + bv);
                pk[3] = (short)f2b(a[3] + bv);
                const int sB = i * 16 + quad * 4;
                *(s4v*)(wbuf + d * 64 + (sB ^ ((d & 7) << 3))) = pk;
            }
        }
        __syncthreads();
        const int rowg0 = m0 + wm * 64;
        const int b  = rowg0 >> 12;
        const int s0 = rowg0 & 4095;
        const int d0 = n0 + wn * 64;
#pragma unroll
        for (int k = 0; k < 8; k++) {
            const int dL = (lane >> 3) + k * 8;
            const int c0 = (lane & 7) * 8;
            short8 vv = *(const short8*)(wbuf + dL * 64 + (c0 ^ ((dL & 7) << 3)));
            *(short8*)(Vt + ((size_t)b * 512 + d0 + dL) * 4096 + s0 + c0) = vv;
        }
    }
}

// ---------- scores: P = sigmoid(Q K^T + bias_bf16), 2-phase dbuf ----------
// z-fastest grid (r7/r10-measured 3.0-3.2 TB/s effective).  NEW: at kt==7 the
// staging slot is idle and lds[cur^1] (32 KB) is dead -> DMA the block's
// 128x128 bf16 bias tile there during the last MFMA phase; epilogue reads
// bias from LDS (kills 64 scalar global-load stalls in the tail).
__global__ __launch_bounds__(256)
void scores_sig(const bf16_t* __restrict__ Qb, const bf16_t* __restrict__ Kb,
                const bf16_t* __restrict__ biasb, bf16_t* __restrict__ P)
{
    __shared__ __align__(16) bf16_t lds[2][16384];   // 64 KB

    const int tid  = threadIdx.x;
    const int lane = tid & 63;
    const int w    = tid >> 6;
    const int wm   = w & 1, wn = w >> 1;
    const int ll   = lane & 15;
    const int quad = lane >> 4;

    const int bx  = blockIdx.x;
    const int z   = bx & 3;
    const int t_  = bx >> 2;              // 0..1023
    const int sup = t_ >> 5;              // 32 supertiles (8 in m x 4 in n)
    const int win = t_ & 31;              // 32 tiles per supertile (4m x 8n)
    const int m0  = ((sup >> 2) * 4 + (win & 3)) * 128;
    const int n0  = ((sup & 3) * 8 + (win >> 2)) * 128;

    const bf16_t* A = Qb + (size_t)z * 2097152;
    const bf16_t* B = Kb + (size_t)z * 2097152;
    bf16_t* out = P + (size_t)z * 16777216;

    auto stage = [&](int kt, int b) {
#pragma unroll
        for (int c = 0; c < 4; ++c) {
            const int base = (c * 4 + w) * 64;
            const int slot = base + lane;
            const int row  = slot >> 3;
            const int kc   = ((slot & 7) ^ (row & 7)) << 3;
            lds_dma16(A + (size_t)(m0 + row) * 512 + kt * 64 + kc, (char*)&lds[b][0]    + base * 16);
            lds_dma16(B + (size_t)(n0 + row) * 512 + kt * 64 + kc, (char*)&lds[b][8192] + base * 16);
        }
    };

    f32x4 acc[4][4];
#pragma unroll
    for (int i = 0; i < 4; i++)
#pragma unroll
        for (int j = 0; j < 4; j++) acc[i][j] = (f32x4){0.f, 0.f, 0.f, 0.f};

    stage(0, 0);
    __syncthreads();
    int cur = 0;
    for (int kt = 0; kt < 8; ++kt) {
        if (kt < 7) {
            stage(kt + 1, cur ^ 1);
        } else {
            // stage 128x128 bf16 bias tile (32 KB) into the dead dbuf half.
            // linear LDS: slot = row*16 + ch (16B chunks), 2048 chunks, 8/thread.
            char* bl = (char*)&lds[cur ^ 1][0];
#pragma unroll
            for (int c = 0; c < 8; ++c) {
                const int bb   = c * 256 + w * 64;   // wave-uniform chunk base
                const int slot = bb + lane;
                const int row  = slot >> 4;
                const int ch   = slot & 15;
                lds_dma16(biasb + (size_t)(m0 + row) * 4096 + n0 + ch * 8,
                          bl + bb * 16);
            }
        }
        const bf16_t* lsA = &lds[cur][0];
        const bf16_t* lsB = &lds[cur][8192];
#pragma unroll
        for (int t = 0; t < 2; t++) {
            short8 af[4], bf[4];
#pragma unroll
            for (int i = 0; i < 4; i++) {
                const int ri = wm * 64 + i * 16 + ll;
                const int rj = wn * 64 + i * 16 + ll;
                af[i] = *(const short8*)(lsA + ri * 64 + (((t * 4 + quad) ^ (ll & 7)) << 3));
                bf[i] = *(const short8*)(lsB + rj * 64 + (((t * 4 + quad) ^ (ll & 7)) << 3));
            }
#pragma unroll
            for (int i = 0; i < 4; i++)
#pragma unroll
                for (int j = 0; j < 4; j++)
                    acc[i][j] = __builtin_amdgcn_mfma_f32_16x16x32_bf16(af[i], bf[j], acc[i][j], 0, 0, 0);
        }
        __syncthreads();
        cur ^= 1;
    }
    // after 8 flips cur==0; bias tile lives in lds[0] (staged at kt==7 into cur(7)^1 = 0)
    const bf16_t* bl = &lds[0][0];

    // sigmoid epilogue: bias from LDS (2-way bank aliasing = free), truncated pack
#pragma unroll
    for (int i = 0; i < 4; i++) {
#pragma unroll
        for (int j = 0; j < 4; j++) {
            const int colL = wn * 64 + j * 16 + ll;      // 0..127
            const int col  = n0 + colL;
            const int rowL0 = wm * 64 + i * 16 + quad * 4;
            f32x4 a = acc[i][j];
#pragma unroll
            for (int r = 0; r < 4; r++) {
                const int rowL = rowL0 + r;
                const float v = a[r] + b2f(bl[rowL * 128 + colL]);
                const float p = __builtin_amdgcn_rcpf(1.f + __expf(-v));
                out[(size_t)(m0 + rowL) * 4096 + col] = (bf16_t)(__float_as_uint(p) >> 16);
            }
        }
    }
}

// ---------- PV: out = P * Vt^T, 128x128, BK=64, 2-phase dbuf, XCD-chunked ----------
// x = bid&7 (XCD); per XCD 16 (m,z)-strips x 4 n-tiles, n innermost -> the 4
// n-siblings sharing a P m-strip run lockstep on ONE XCD (r9-verified win).
__global__ __launch_bounds__(256)
void pv_gemm(const bf16_t* __restrict__ P, const bf16_t* __restrict__ Vt,
             float* __restrict__ outg)
{
    __shared__ __align__(16) bf16_t lds[2][16384];   // 64 KB

    const int tid  = threadIdx.x;
    const int lane = tid & 63;
    const int w    = tid >> 6;
    const int wm   = w & 1, wn = w >> 1;
    const int ll   = lane & 15;
    const int quad = lane >> 4;

    const int bid   = blockIdx.x;        // 0..511
    const int x     = bid & 7;
    const int g     = bid >> 3;          // 0..63
    const int strip = x * 16 + (g >> 2); // 0..127
    const int n0    = (g & 3) * 128;
    const int m0    = (strip & 31) * 128;
    const int z     = strip >> 5;

    const bf16_t* A = P + (size_t)z * 16777216;   // [4096][4096]
    const bf16_t* B = Vt + (size_t)z * 2097152;   // [512][4096]
    float* out = outg + (size_t)z * 2097152;

    auto stage = [&](int kt, int b) {
#pragma unroll
        for (int c = 0; c < 4; ++c) {
            const int base = (c * 4 + w) * 64;
            const int slot = base + lane;
            const int row  = slot >> 3;
            const int kc   = ((slot & 7) ^ (row & 7)) << 3;
            lds_dma16(A + (size_t)(m0 + row) * 4096 + kt * 64 + kc, (char*)&lds[b][0]    + base * 16);
            lds_dma16(B + (size_t)(n0 + row) * 4096 + kt * 64 + kc, (char*)&lds[b][8192] + base * 16);
        }
    };

    f32x4 acc[4][4];
#pragma unroll
    for (int i = 0; i < 4; i++)
#pragma unroll
        for (int j = 0; j < 4; j++) acc[i][j] = (f32x4){0.f, 0.f, 0.f, 0.f};

    stage(0, 0);
    __syncthreads();
    int cur = 0;
    for (int kt = 0; kt < 64; ++kt) {
        if (kt < 63) stage(kt + 1, cur ^ 1);
        const bf16_t* lsA = &lds[cur][0];
        const bf16_t* lsB = &lds[cur][8192];
#pragma unroll
        for (int t = 0; t < 2; t++) {
            short8 af[4], bf[4];
#pragma unroll
            for (int i = 0; i < 4; i++) {
                const int ri = wm * 64 + i * 16 + ll;
                const int rj = wn * 64 + i * 16 + ll;
                af[i] = *(const short8*)(lsA + ri * 64 + (((t * 4 + quad) ^ (ll & 7)) << 3));
                bf[i] = *(const short8*)(lsB + rj * 64 + (((t * 4 + quad) ^ (ll & 7)) << 3));
            }
#pragma unroll
            for (int i = 0; i < 4; i++)
#pragma unroll
                for (int j = 0; j < 4; j++)
                    acc[i][j] = __builtin_amdgcn_mfma_f32_16x16x32_bf16(af[i], bf[j], acc[i][j], 0, 0, 0);
        }
        __syncthreads();
        cur ^= 1;
    }

#pragma unroll
    for (int i = 0; i < 4; i++) {
#pragma unroll
        for (int j = 0; j < 4; j++) {
            const int col  = n0 + wn * 64 + j * 16 + ll;
            const int rowb = m0 + wm * 64 + i * 16 + quad * 4;
            f32x4 a = acc[i][j];
#pragma unroll
            for (int r = 0; r < 4; r++)
                out[(size_t)(rowb + r) * 512 + col] = a[r];
        }
    }
}

extern "C" void kernel_launch(void* const* d_in, const int* in_sizes, int n_in,
                              void* d_out, int out_size, void* d_ws, size_t ws_size,
                              hipStream_t stream) {
    (void)in_sizes; (void)n_in; (void)out_size; (void)ws_size;
    const float* x    = (const float*)d_in[0];
    const float* bias = (const float*)d_in[1];
    const float* Wq_w = (const float*)d_in[2];
    const float* Wq_b = (const float*)d_in[3];
    const float* Wk_w = (const float*)d_in[4];
    const float* Wk_b = (const float*)d_in[5];
    const float* Wv_w = (const float*)d_in[6];
    const float* Wv_b = (const float*)d_in[7];
    float* out = (float*)d_out;

    // workspace layout (bf16 elements)
    bf16_t* Xb = (bf16_t*)d_ws;                    // 16384 x 512
    bf16_t* Wb = Xb + (size_t)16384 * 512;         // 3 x 512 x 512
    bf16_t* Qb = Wb + (size_t)3 * 512 * 512;       // 16384 x 512 (pre-scaled 1/sqrt(D))
    bf16_t* Kb = Qb + (size_t)16384 * 512;         // 16384 x 512
    bf16_t* Vt = Kb + (size_t)16384 * 512;         // 4 x 512 x 4096 (transposed V)
    bf16_t* P  = Vt + (size_t)16384 * 512;         // 4 x 4096 x 4096
    // bf16 bias scratch: d_out (33,554,432 B) == 4096*4096*2 B exactly; out is
    // dead until pv_gemm overwrites it at the end (r7-r10-verified aliasing).
    bf16_t* Bb = (bf16_t*)d_out;

    // all input conversions in one launch (x + 3 weight matrices)
    cvt_all<<<8960, 256, 0, stream>>>(x, Xb, Wq_w, Wk_w, Wv_w, Wb);

    // projections + bias cvt streamed into the k-loop (overlap)
    proj_all<<<1536, 256, 0, stream>>>(Xb, Wb, Wq_b, Wk_b, Wv_b, Qb, Kb, Vt,
                                       bias, Bb);
    // scores + sigmoid (z-fastest grid, bf16 bias staged to LDS at kt==7)
    scores_sig<<<4096, 256, 0, stream>>>(Qb, Kb, Bb, P);
    // out = P * V (2-phase dbuf, XCD-chunked w/ n innermost per P-strip)
    pv_gemm<<<512, 256, 0, stream>>>(P, Vt, out);
}